// Round 1
// baseline (1640.155 us; speedup 1.0000x reference)
//
#include <hip/hip_runtime.h>
#include <stdint.h>

#pragma clang fp contract(off)

// ---- problem dims ----
#define T_    4
#define B_    16
#define C_    512
#define HID_  2048
#define NPIX  256
#define TB_   64          // T_*B_
#define M1_   2097152     // B_*C_*NPIX   (per-timestep plane, C channels)
#define M2_   8388608     // B_*HID_*NPIX (per-timestep plane, HID channels)
#define OUT1_ 8388608     // T_*M1_

// ---- workspace layout (bytes) ----
constexpr size_t OFF_SC_Q    = 0;                       // 512 f32
constexpr size_t OFF_SC_K    = 2048;
constexpr size_t OFF_SC_V    = 4096;
constexpr size_t OFF_SC_PROJ = 6144;
constexpr size_t OFF_SC_FC1  = 8192;                    // 2048 f32
constexpr size_t OFF_SC_FC2  = 16384;
constexpr size_t SPK_BYTES   = 8388608;                 // T*B*C*N u8
constexpr size_t OFF_XS      = 18432;
constexpr size_t OFF_QS      = OFF_XS  + SPK_BYTES;
constexpr size_t OFF_KS      = OFF_QS  + SPK_BYTES;
constexpr size_t OFF_VS      = OFF_KS  + SPK_BYTES;
constexpr size_t OFF_KVS     = OFF_VS  + SPK_BYTES;     // 32768 u8
constexpr size_t OFF_H1      = OFF_KVS + 32768;
constexpr size_t OFF_H2      = OFF_H1  + SPK_BYTES;     // 4*SPK u8 (HID spikes)
constexpr size_t OFF_XATTN   = OFF_H2  + 4*SPK_BYTES;   // 33554432 f32 bytes
constexpr size_t OFF_BIG     = OFF_XATTN + 33554432;    // union: ybuf(33.5MB) / yfc1(134MB)

// ---- BN scale prep: sc = g / sqrt(var + 1e-5) ----
__global__ void prep_sc_kernel(const float* __restrict__ bn, float* __restrict__ sc, int Cn) {
    int c = blockIdx.x * blockDim.x + threadIdx.x;
    if (c < Cn) {
        float g   = bn[c];
        float var = bn[3 * Cn + c];
        sc[c] = g / sqrtf(var + 1e-5f);
    }
}

// ---- LIF forward over T (hard reset, decay_input=True, tau=2) ----
// y: [T, M] f32 membrane input; s: [T, M] u8 spikes
__global__ void lif_kernel(const float* __restrict__ y, unsigned char* __restrict__ s,
                           int M, float vth) {
    int i = blockIdx.x * blockDim.x + threadIdx.x;
    if (i >= M) return;
    float v = 0.0f;
    #pragma unroll
    for (int t = 0; t < T_; ++t) {
        float x = y[(size_t)t * M + i];
        v = v + (x - v) / 2.0f;
        float d = v - vth;
        unsigned char sp = (d >= 0.0f) ? 1 : 0;
        s[(size_t)t * M + i] = sp;
        if (sp) v = 0.0f;
    }
}

// ---- kv = sum_n (k & v)  then LIF(vth=0.5) ----
// ks, vs: [T,B,C,N] u8 spikes;  kvs: [T,B,C] u8 spikes
__global__ void kv_lif_kernel(const unsigned char* __restrict__ ks,
                              const unsigned char* __restrict__ vs,
                              unsigned char* __restrict__ kvs) {
    int i = blockIdx.x * blockDim.x + threadIdx.x;   // over B_*C_
    if (i >= B_ * C_) return;
    int b = i >> 9;          // /C_
    int c = i & (C_ - 1);
    float v = 0.0f;
    for (int t = 0; t < T_; ++t) {
        size_t base = ((size_t)((t * B_ + b) * C_) + c) * NPIX;
        const unsigned long long* kp = (const unsigned long long*)(ks + base);
        const unsigned long long* vp = (const unsigned long long*)(vs + base);
        int sum = 0;
        #pragma unroll
        for (int w = 0; w < NPIX / 8; ++w)
            sum += __popcll(kp[w] & vp[w]);    // bytes are 0/1 -> bit0 only
        float x = (float)sum;                  // exact integer <= 256
        v = v + (x - v) / 2.0f;
        float d = v - 0.5f;
        unsigned char sp = (d >= 0.0f) ? 1 : 0;
        kvs[(size_t)(t * B_ + b) * C_ + c] = sp;
        if (sp) v = 0.0f;
    }
}

// ---- vh output: vh[t,b,h,n,ch] = v[t,b,h*64+ch,n] as f32 ----
__global__ void vh_write_kernel(const unsigned char* __restrict__ vs, float* __restrict__ out2) {
    int slab = blockIdx.x;            // (t*B+b)*8 + h, 512 slabs
    int tb = slab >> 3;
    int h  = slab & 7;
    const unsigned char* src = vs + ((size_t)tb * C_ + h * 64) * NPIX;   // [64ch][256n]
    float* dst = out2 + (size_t)slab * 16384;
    for (int j = threadIdx.x; j < 16384; j += blockDim.x) {
        int ch = j & 63;
        int n  = j >> 6;
        dst[j] = src[ch * NPIX + n] ? 1.0f : 0.0f;
    }
}

// ---- batched spike GEMM + BN (+bias, +mask on K rows, +residual) ----
// S: [TB, Cin, 256] u8; mask: [TB, Cin] u8 or null; W: [Cout, Cin] f32
// out[z, o, p] = BN( sum_i W[o,i]*S[z,i,p]*mask[z,i] + bias[o] ) + res[z,o,p]
#define BMT 128
#define BPT 128
#define BKT 16
__global__ __launch_bounds__(256) void gemm_bn_kernel(
        const unsigned char* __restrict__ S,
        const unsigned char* __restrict__ mask,
        const float* __restrict__ W,
        const float* __restrict__ bias,
        const float* __restrict__ bnp,   // [4, Cout]: g, be, m, var
        const float* __restrict__ sc,    // [Cout]
        const float* __restrict__ res,   // same layout as out, or null
        float* __restrict__ out,
        int Cin, int Cout) {
    __shared__ float Ws[BKT][BMT + 4];
    __shared__ float Ss[BKT][BPT + 4];
    int z  = blockIdx.z;
    int o0 = blockIdx.y * BMT;
    int p0 = blockIdx.x * BPT;
    int tid = threadIdx.x;
    int tx = tid & 15, ty = tid >> 4;

    float acc[8][8];
    #pragma unroll
    for (int i = 0; i < 8; ++i)
        #pragma unroll
        for (int j = 0; j < 8; ++j) acc[i][j] = 0.0f;

    const unsigned char* Sb = S + (size_t)z * Cin * NPIX;
    const unsigned char* Mb = mask ? (mask + (size_t)z * Cin) : nullptr;

    for (int k0 = 0; k0 < Cin; k0 += BKT) {
        // W tile: 128 o x 16 k
        {
            int kk = tid & 15;
            int ob = tid >> 4;   // 0..15
            #pragma unroll
            for (int r = 0; r < 8; ++r) {
                int o = ob + r * 16;
                Ws[kk][o] = W[(size_t)(o0 + o) * Cin + k0 + kk];
            }
        }
        // S tile: 16 k x 128 p (u8 -> f32, masked)
        {
            int c4  = tid & 31;   // col group of 4
            int row = tid >> 5;   // 0..7
            #pragma unroll
            for (int r = 0; r < 2; ++r) {
                int kk = row + r * 8;
                float m = Mb ? (float)Mb[k0 + kk] : 1.0f;
                uchar4 u = *(const uchar4*)(Sb + (size_t)(k0 + kk) * NPIX + p0 + (c4 << 2));
                Ss[kk][(c4 << 2) + 0] = m * (float)u.x;
                Ss[kk][(c4 << 2) + 1] = m * (float)u.y;
                Ss[kk][(c4 << 2) + 2] = m * (float)u.z;
                Ss[kk][(c4 << 2) + 3] = m * (float)u.w;
            }
        }
        __syncthreads();
        #pragma unroll
        for (int kk = 0; kk < BKT; ++kk) {
            float a[8], b[8];
            #pragma unroll
            for (int i = 0; i < 8; ++i) a[i] = Ws[kk][ty * 8 + i];
            #pragma unroll
            for (int j = 0; j < 8; ++j) b[j] = Ss[kk][tx * 8 + j];
            #pragma unroll
            for (int i = 0; i < 8; ++i)
                #pragma unroll
                for (int j = 0; j < 8; ++j)
                    acc[i][j] = __builtin_fmaf(a[i], b[j], acc[i][j]);
        }
        __syncthreads();
    }

    // epilogue: (+bias) -> (y - m)*sc + be -> (+res)
    #pragma unroll
    for (int i = 0; i < 8; ++i) {
        int o = o0 + ty * 8 + i;
        float be  = bnp[Cout + o];
        float m_  = bnp[2 * Cout + o];
        float scv = sc[o];
        float bv  = bias ? bias[o] : 0.0f;
        #pragma unroll
        for (int j = 0; j < 8; ++j) {
            int p = p0 + tx * 8 + j;
            float y = acc[i][j] + bv;
            float zv = (y - m_) * scv + be;
            size_t idx = ((size_t)z * Cout + o) * NPIX + p;
            if (res) zv = zv + res[idx];
            out[idx] = zv;
        }
    }
}

extern "C" void kernel_launch(void* const* d_in, const int* in_sizes, int n_in,
                              void* d_out, int out_size, void* d_ws, size_t ws_size,
                              hipStream_t stream) {
    (void)in_sizes; (void)n_in; (void)out_size; (void)ws_size;
    const float* x       = (const float*)d_in[0];
    const float* q_w     = (const float*)d_in[1];
    const float* k_w     = (const float*)d_in[2];
    const float* v_w     = (const float*)d_in[3];
    const float* proj_w  = (const float*)d_in[4];
    const float* proj_b  = (const float*)d_in[5];
    const float* fc1_w   = (const float*)d_in[6];
    const float* fc1_b   = (const float*)d_in[7];
    const float* fc2_w   = (const float*)d_in[8];
    const float* fc2_b   = (const float*)d_in[9];
    const float* q_bn    = (const float*)d_in[10];
    const float* k_bn    = (const float*)d_in[11];
    const float* v_bn    = (const float*)d_in[12];
    const float* proj_bn = (const float*)d_in[13];
    const float* fc1_bn  = (const float*)d_in[14];
    const float* fc2_bn  = (const float*)d_in[15];

    char* ws = (char*)d_ws;
    float* sc_q    = (float*)(ws + OFF_SC_Q);
    float* sc_k    = (float*)(ws + OFF_SC_K);
    float* sc_v    = (float*)(ws + OFF_SC_V);
    float* sc_proj = (float*)(ws + OFF_SC_PROJ);
    float* sc_fc1  = (float*)(ws + OFF_SC_FC1);
    float* sc_fc2  = (float*)(ws + OFF_SC_FC2);
    unsigned char* xs_spk = (unsigned char*)(ws + OFF_XS);
    unsigned char* q_spk  = (unsigned char*)(ws + OFF_QS);
    unsigned char* k_spk  = (unsigned char*)(ws + OFF_KS);
    unsigned char* v_spk  = (unsigned char*)(ws + OFF_VS);
    unsigned char* kv_s   = (unsigned char*)(ws + OFF_KVS);
    unsigned char* h1_spk = (unsigned char*)(ws + OFF_H1);
    unsigned char* h2_spk = (unsigned char*)(ws + OFF_H2);
    float* x_attn = (float*)(ws + OFF_XATTN);
    float* ybuf   = (float*)(ws + OFF_BIG);   // q/k/v conv out (reused)
    float* yfc1   = (float*)(ws + OFF_BIG);   // fc1 conv out (after ybuf dead)

    float* out1 = (float*)d_out;
    float* out2 = out1 + OUT1_;

    // BN scales
    prep_sc_kernel<<<2, 256, 0, stream>>>(q_bn,    sc_q,    C_);
    prep_sc_kernel<<<2, 256, 0, stream>>>(k_bn,    sc_k,    C_);
    prep_sc_kernel<<<2, 256, 0, stream>>>(v_bn,    sc_v,    C_);
    prep_sc_kernel<<<2, 256, 0, stream>>>(proj_bn, sc_proj, C_);
    prep_sc_kernel<<<8, 256, 0, stream>>>(fc1_bn,  sc_fc1,  HID_);
    prep_sc_kernel<<<2, 256, 0, stream>>>(fc2_bn,  sc_fc2,  C_);

    dim3 g512(2, C_ / BMT, TB_);      // Cout=512 GEMMs
    dim3 gfc1(2, HID_ / BMT, TB_);    // Cout=2048

    // shortcut LIF on x
    lif_kernel<<<(M1_ + 255) / 256, 256, 0, stream>>>(x, xs_spk, M1_, 1.0f);

    // q / k / v conv+BN then LIF
    gemm_bn_kernel<<<g512, 256, 0, stream>>>(xs_spk, nullptr, q_w, nullptr, q_bn, sc_q, nullptr, ybuf, C_, C_);
    lif_kernel<<<(M1_ + 255) / 256, 256, 0, stream>>>(ybuf, q_spk, M1_, 1.0f);
    gemm_bn_kernel<<<g512, 256, 0, stream>>>(xs_spk, nullptr, k_w, nullptr, k_bn, sc_k, nullptr, ybuf, C_, C_);
    lif_kernel<<<(M1_ + 255) / 256, 256, 0, stream>>>(ybuf, k_spk, M1_, 1.0f);
    gemm_bn_kernel<<<g512, 256, 0, stream>>>(xs_spk, nullptr, v_w, nullptr, v_bn, sc_v, nullptr, ybuf, C_, C_);
    lif_kernel<<<(M1_ + 255) / 256, 256, 0, stream>>>(ybuf, v_spk, M1_, 1.0f);

    // kv reduce + talking-heads LIF; vh output
    kv_lif_kernel<<<(B_ * C_ + 255) / 256, 256, 0, stream>>>(k_spk, v_spk, kv_s);
    vh_write_kernel<<<512, 256, 0, stream>>>(v_spk, out2);

    // proj conv on att = q & kv (mask fused), +BN +residual(x)
    gemm_bn_kernel<<<g512, 256, 0, stream>>>(q_spk, kv_s, proj_w, proj_b, proj_bn, sc_proj, x, x_attn, C_, C_);

    // MLP
    lif_kernel<<<(M1_ + 255) / 256, 256, 0, stream>>>(x_attn, h1_spk, M1_, 1.0f);
    gemm_bn_kernel<<<gfc1, 256, 0, stream>>>(h1_spk, nullptr, fc1_w, fc1_b, fc1_bn, sc_fc1, nullptr, yfc1, C_, HID_);
    lif_kernel<<<(M2_ + 255) / 256, 256, 0, stream>>>(yfc1, h2_spk, M2_, 1.0f);
    gemm_bn_kernel<<<g512, 256, 0, stream>>>(h2_spk, nullptr, fc2_w, fc2_b, fc2_bn, sc_fc2, x_attn, out1, HID_, C_);
}

// Round 2
// 558.650 us; speedup vs baseline: 2.9359x; 2.9359x over previous
//
#include <hip/hip_runtime.h>
#include <stdint.h>

#pragma clang fp contract(off)

typedef _Float16 f16x8 __attribute__((ext_vector_type(8)));
typedef float f32x4 __attribute__((ext_vector_type(4)));
typedef unsigned short u16;
typedef u16 u16x8 __attribute__((ext_vector_type(8)));

#define T_   4
#define B_   16
#define C_   512
#define HID_ 2048
#define NPIX 256
#define Z_   64            // T_*B_

// ---------------- workspace layout (bytes) ----------------
constexpr size_t OFF_SC_Q    = 0;         // each sc slot 8KB
constexpr size_t OFF_SC_K    = 8192;
constexpr size_t OFF_SC_V    = 16384;
constexpr size_t OFF_SC_PROJ = 24576;
constexpr size_t OFF_SC_FC1  = 32768;
constexpr size_t OFF_SC_FC2  = 40960;
constexpr size_t OFF_PRESUM  = 65536;     // 64*512 f32 = 128KB
constexpr size_t OFF_MASK    = 196608;    // 64*512 u16 = 64KB
constexpr size_t OFF_W       = 262144;
constexpr size_t WSZ_S       = 524288;    // 512*512*2
constexpr size_t WSZ_L       = 2097152;   // 2048*512*2
constexpr size_t OFF_QHI = OFF_W;
constexpr size_t OFF_QLO = OFF_QHI + WSZ_S;
constexpr size_t OFF_KHI = OFF_QLO + WSZ_S;
constexpr size_t OFF_KLO = OFF_KHI + WSZ_S;
constexpr size_t OFF_VHI = OFF_KLO + WSZ_S;
constexpr size_t OFF_VLO = OFF_VHI + WSZ_S;
constexpr size_t OFF_PHI = OFF_VLO + WSZ_S;
constexpr size_t OFF_PLO = OFF_PHI + WSZ_S;
constexpr size_t OFF_F1HI = OFF_PLO + WSZ_S;
constexpr size_t OFF_F1LO = OFF_F1HI + WSZ_L;
constexpr size_t OFF_F2HI = OFF_F1LO + WSZ_L;
constexpr size_t OFF_F2LO = OFF_F2HI + WSZ_L;
constexpr size_t OFF_SPK  = OFF_F2LO + WSZ_L;          // 12845056
constexpr size_t SPKB     = 16777216;                  // 64*256*512*2
constexpr size_t OFF_SPK_A = OFF_SPK;                  // xs -> att -> h1
constexpr size_t OFF_SPK_B = OFF_SPK + SPKB;           // q   -> h2 (B..E)
constexpr size_t OFF_SPK_C = OFF_SPK + 2*SPKB;         // k
constexpr size_t OFF_SPK_D = OFF_SPK + 3*SPKB;         // v
constexpr size_t OFF_YBIG  = OFF_SPK + 5*SPKB;         // 134217728 f32 bytes

// ---------------- prep: BN scale ----------------
__global__ void prep_sc_kernel(const float* __restrict__ bn, float* __restrict__ sc, int Cn) {
    int c = blockIdx.x * blockDim.x + threadIdx.x;
    if (c < Cn) sc[c] = bn[c] / sqrtf(bn[3 * Cn + c] + 1e-5f);
}

// ---------------- prep: f16 2-split of fp32 weights (lo pre-scaled by 2^11) ----------------
__global__ void prep_split_kernel(const float* __restrict__ W, u16* __restrict__ hi,
                                  u16* __restrict__ lo, int n) {
    int i = blockIdx.x * 256 + threadIdx.x;
    if (i >= n) return;
    float w = W[i];
    _Float16 h = (_Float16)w;
    float d = w - (float)h;               // exact (Sterbenz)
    _Float16 l = (_Float16)(d * 2048.0f); // keep lo in f16 normal range
    hi[i] = *(const u16*)&h;
    lo[i] = *(const u16*)&l;
}

// ---------------- LIF + transpose: y[T,B,Cf,N] f32 -> spk[z][n][c] f16 ----------------
__global__ __launch_bounds__(256) void lif_transpose_kernel(
        const float* __restrict__ y, u16* __restrict__ spk, int Cf) {
    __shared__ __align__(16) u16 tile[256 * 72];   // [t*64+nn][72]
    int b  = blockIdx.z;
    int c0 = blockIdx.y * 64;
    int n0 = blockIdx.x * 64;
    int tid = threadIdx.x;
    int nn = tid & 63;
    int cg = tid >> 6;
    size_t tstride = (size_t)B_ * Cf * NPIX;
    for (int e = 0; e < 16; ++e) {
        int ci = cg * 16 + e;
        size_t base = ((size_t)b * Cf + c0 + ci) * NPIX + n0 + nn;
        float v = 0.0f;
        #pragma unroll
        for (int t = 0; t < T_; ++t) {
            float x = y[base + (size_t)t * tstride];
            v = v + (x - v) * 0.5f;
            u16 s = 0;
            if (v >= 1.0f) { s = 0x3C00; v = 0.0f; }
            tile[(t * 64 + nn) * 72 + ci] = s;
        }
    }
    __syncthreads();
    int t = tid >> 6, n2 = tid & 63;
    const u16* srow = &tile[(t * 64 + n2) * 72];
    u16* drow = spk + ((size_t)((t * B_ + b) * NPIX) + n0 + n2) * Cf + c0;
    #pragma unroll
    for (int kk = 0; kk < 8; ++kk)
        *(u16x8*)(drow + kk * 8) = *(const u16x8*)(srow + kk * 8);
}

// ---------------- kv presum: counts of (k & v) over n, per (z,c) ----------------
__global__ void kv_presum_kernel(const u16* __restrict__ k, const u16* __restrict__ v,
                                 float* __restrict__ presum) {
    int z = blockIdx.x;
    int tid = threadIdx.x;
    const uint* kp = (const uint*)(k + (size_t)z * NPIX * C_);
    const uint* vp = (const uint*)(v + (size_t)z * NPIX * C_);
    int s0 = 0, s1 = 0;
    for (int n = 0; n < NPIX; ++n) {
        uint a = kp[n * 256 + tid];
        uint b = vp[n * 256 + tid];
        uint c = a & b;                 // f16 1.0 = 0x3C00; both-one iff bit10/bit26 set
        s0 += (c >> 10) & 1;
        s1 += (c >> 26) & 1;
    }
    presum[z * C_ + 2 * tid]     = (float)s0;
    presum[z * C_ + 2 * tid + 1] = (float)s1;
}

// ---------------- kv LIF (vth=0.5) -> mask u16 ----------------
__global__ void kv_lif_mask_kernel(const float* __restrict__ presum, u16* __restrict__ mask) {
    int i = blockIdx.x * 256 + threadIdx.x;   // 8192 = B_*C_
    int b = i >> 9, c = i & (C_ - 1);
    float v = 0.0f;
    #pragma unroll
    for (int t = 0; t < T_; ++t) {
        float x = presum[((t * B_ + b) << 9) + c];
        v = v + (x - v) * 0.5f;
        u16 m = 0;
        if (v >= 0.5f) { m = 0xFFFF; v = 0.0f; }
        mask[((t * B_ + b) << 9) + c] = m;
    }
}

// ---------------- att = q & mask (broadcast over n) ----------------
__global__ void att_apply_kernel(const u16* __restrict__ q, const u16* __restrict__ mask,
                                 u16* __restrict__ att) {
    size_t i = (size_t)blockIdx.x * 256 + threadIdx.x;  // over 64*256*128 uint2-groups
    int z  = (int)(i >> 15);
    int c4 = (int)(i & 127);
    uint2 qv = ((const uint2*)q)[i];
    uint2 mv = ((const uint2*)(mask + (size_t)z * C_))[c4];
    uint2 r;
    r.x = qv.x & mv.x;
    r.y = qv.y & mv.y;
    ((uint2*)att)[i] = r;
}

// ---------------- vh output: out2[(z*8+h)][n][ch] = v[z][n][h*64+ch] as f32 ----------------
__global__ void vh_write_kernel(const u16* __restrict__ v, float* __restrict__ out2) {
    int slab = blockIdx.x;           // z*8+h
    int z = slab >> 3, h = slab & 7;
    int tid = threadIdx.x;
    int n = tid >> 2, cg = tid & 3;
    for (int it = 0; it < 4; ++it) {
        int nn = n + it * 64;
        const u16* src = v + ((size_t)z * NPIX + nn) * C_ + h * 64 + cg * 16;
        float* dst = out2 + ((size_t)slab * NPIX + nn) * 64 + cg * 16;
        #pragma unroll
        for (int j = 0; j < 16; ++j) dst[j] = src[j] ? 1.0f : 0.0f;
    }
}

// ---------------- MFMA spike GEMM, 128x128 tile, BK=64, f16 2-split, BN fused ----------------
__global__ __launch_bounds__(256, 2) void gemm_kernel(
        const u16* __restrict__ S,     // [64][256][Cin] f16 spikes
        const u16* __restrict__ Whi,   // [Cout][Cin]
        const u16* __restrict__ Wlo,
        const float* __restrict__ bias,
        const float* __restrict__ bnp, // [4][Cout]
        const float* __restrict__ sc,  // [Cout]
        const float* res,              // [z][Cout][256] or null (may alias out)
        float* out,                    // [z][Cout][256]
        int Cin, int Cout) {
    __shared__ __align__(16) u16 lds[24576];  // Ahi[0..8191] Alo[8192..] B[16384..]
    const int tid  = threadIdx.x;
    const int lane = tid & 63;
    const int wid  = tid >> 6;
    const int wm = wid >> 1, wn = wid & 1;
    const int r15 = lane & 15, quad = lane >> 4;
    const int z  = blockIdx.z;
    const int o0 = blockIdx.y * 128;
    const int p0 = blockIdx.x * 128;

    f32x4 acc1[4][4], acc2[4][4];
    #pragma unroll
    for (int a = 0; a < 4; ++a)
        #pragma unroll
        for (int b = 0; b < 4; ++b) {
            acc1[a][b] = (f32x4){0.f, 0.f, 0.f, 0.f};
            acc2[a][b] = (f32x4){0.f, 0.f, 0.f, 0.f};
        }

    const u16* gb0 = Whi + (size_t)o0 * Cin;
    const u16* gb1 = Wlo + (size_t)o0 * Cin;
    const u16* gb2 = S + ((size_t)z * NPIX + p0) * Cin;
    const int srow = lane >> 3;   // staging row within 8-row group
    const int sj   = lane & 7;    // staging chunk slot

    for (int k0 = 0; k0 < Cin; k0 += 64) {
        __syncthreads();
        #pragma unroll
        for (int e = 0; e < 12; ++e) {
            int g   = wid * 12 + e;            // 0..47
            int buf = g >> 4;                  // 0=Ahi 1=Alo 2=B
            int rg  = g & 15;                  // 8-row group
            int m   = rg * 8 + srow;           // tile row 0..127
            int jg  = sj ^ (m & 7);            // XOR-swizzle source chunk
            const u16* src = (buf == 0 ? gb0 : (buf == 1 ? gb1 : gb2))
                             + (size_t)m * Cin + k0 + jg * 8;
            char* dst = (char*)lds + buf * 16384 + rg * 1024;
            __builtin_amdgcn_global_load_lds(
                (const __attribute__((address_space(1))) void*)(uintptr_t)(const void*)src,
                (__attribute__((address_space(3))) void*)(uintptr_t)(void*)dst,
                16, 0, 0);
        }
        __syncthreads();
        #pragma unroll
        for (int ks = 0; ks < 2; ++ks) {
            int cj = ks * 4 + quad;
            f16x8 af[4], al[4], bf[4];
            #pragma unroll
            for (int mt = 0; mt < 4; ++mt) {
                int m = wm * 64 + mt * 16 + r15;
                int ad = m * 64 + ((cj ^ (m & 7)) << 3);
                af[mt] = *(const f16x8*)(lds + ad);
                al[mt] = *(const f16x8*)(lds + 8192 + ad);
            }
            #pragma unroll
            for (int nt = 0; nt < 4; ++nt) {
                int n = wn * 64 + nt * 16 + r15;
                int ad = n * 64 + ((cj ^ (n & 7)) << 3);
                bf[nt] = *(const f16x8*)(lds + 16384 + ad);
            }
            #pragma unroll
            for (int mt = 0; mt < 4; ++mt)
                #pragma unroll
                for (int nt = 0; nt < 4; ++nt) {
                    acc1[mt][nt] = __builtin_amdgcn_mfma_f32_16x16x32_f16(af[mt], bf[nt], acc1[mt][nt], 0, 0, 0);
                    acc2[mt][nt] = __builtin_amdgcn_mfma_f32_16x16x32_f16(al[mt], bf[nt], acc2[mt][nt], 0, 0, 0);
                }
        }
    }

    const float inv2048 = 1.0f / 2048.0f;
    #pragma unroll
    for (int mt = 0; mt < 4; ++mt) {
        int ob = o0 + wm * 64 + mt * 16 + quad * 4;
        float scv[4], mm[4], bb[4], bv[4];
        #pragma unroll
        for (int r = 0; r < 4; ++r) {
            int o = ob + r;
            scv[r] = sc[o];
            mm[r]  = bnp[2 * Cout + o];
            bb[r]  = bnp[Cout + o];
            bv[r]  = bias ? bias[o] : 0.0f;
        }
        #pragma unroll
        for (int nt = 0; nt < 4; ++nt) {
            int p = p0 + wn * 64 + nt * 16 + r15;
            #pragma unroll
            for (int r = 0; r < 4; ++r) {
                float y = acc1[mt][nt][r] + acc2[mt][nt][r] * inv2048 + bv[r];
                float val = (y - mm[r]) * scv[r] + bb[r];
                size_t idx = ((size_t)z * Cout + ob + r) * NPIX + p;
                if (res) val += res[idx];
                out[idx] = val;
            }
        }
    }
}

extern "C" void kernel_launch(void* const* d_in, const int* in_sizes, int n_in,
                              void* d_out, int out_size, void* d_ws, size_t ws_size,
                              hipStream_t stream) {
    (void)in_sizes; (void)n_in; (void)out_size; (void)ws_size;
    const float* x       = (const float*)d_in[0];
    const float* q_w     = (const float*)d_in[1];
    const float* k_w     = (const float*)d_in[2];
    const float* v_w     = (const float*)d_in[3];
    const float* proj_w  = (const float*)d_in[4];
    const float* proj_b  = (const float*)d_in[5];
    const float* fc1_w   = (const float*)d_in[6];
    const float* fc1_b   = (const float*)d_in[7];
    const float* fc2_w   = (const float*)d_in[8];
    const float* fc2_b   = (const float*)d_in[9];
    const float* q_bn    = (const float*)d_in[10];
    const float* k_bn    = (const float*)d_in[11];
    const float* v_bn    = (const float*)d_in[12];
    const float* proj_bn = (const float*)d_in[13];
    const float* fc1_bn  = (const float*)d_in[14];
    const float* fc2_bn  = (const float*)d_in[15];

    char* ws = (char*)d_ws;
    float* sc_q    = (float*)(ws + OFF_SC_Q);
    float* sc_k    = (float*)(ws + OFF_SC_K);
    float* sc_v    = (float*)(ws + OFF_SC_V);
    float* sc_proj = (float*)(ws + OFF_SC_PROJ);
    float* sc_fc1  = (float*)(ws + OFF_SC_FC1);
    float* sc_fc2  = (float*)(ws + OFF_SC_FC2);
    float* presum  = (float*)(ws + OFF_PRESUM);
    u16*   maskp   = (u16*)(ws + OFF_MASK);
    u16 *qhi = (u16*)(ws + OFF_QHI), *qlo = (u16*)(ws + OFF_QLO);
    u16 *khi = (u16*)(ws + OFF_KHI), *klo = (u16*)(ws + OFF_KLO);
    u16 *vhi = (u16*)(ws + OFF_VHI), *vlo = (u16*)(ws + OFF_VLO);
    u16 *phi = (u16*)(ws + OFF_PHI), *plo = (u16*)(ws + OFF_PLO);
    u16 *f1hi = (u16*)(ws + OFF_F1HI), *f1lo = (u16*)(ws + OFF_F1LO);
    u16 *f2hi = (u16*)(ws + OFF_F2HI), *f2lo = (u16*)(ws + OFF_F2LO);
    u16* spkA = (u16*)(ws + OFF_SPK_A);   // xs -> att -> h1
    u16* spkB = (u16*)(ws + OFF_SPK_B);   // q -> h2 head
    u16* spkC = (u16*)(ws + OFF_SPK_C);   // k
    u16* spkD = (u16*)(ws + OFF_SPK_D);   // v
    u16* h2   = spkB;                     // h2 spans B..E (67MB)
    float* ybuf = (float*)(ws + OFF_YBIG);
    float* yfc1 = (float*)(ws + OFF_YBIG);

    float* out1 = (float*)d_out;
    float* out2 = out1 + 8388608;
    float* x_attn = out1;                 // x_attn lives in out1 region until fc2 overwrites in-place

    // BN scales
    prep_sc_kernel<<<2, 256, 0, stream>>>(q_bn,    sc_q,    C_);
    prep_sc_kernel<<<2, 256, 0, stream>>>(k_bn,    sc_k,    C_);
    prep_sc_kernel<<<2, 256, 0, stream>>>(v_bn,    sc_v,    C_);
    prep_sc_kernel<<<2, 256, 0, stream>>>(proj_bn, sc_proj, C_);
    prep_sc_kernel<<<8, 256, 0, stream>>>(fc1_bn,  sc_fc1,  HID_);
    prep_sc_kernel<<<2, 256, 0, stream>>>(fc2_bn,  sc_fc2,  C_);

    // weight splits
    prep_split_kernel<<<1024, 256, 0, stream>>>(q_w,    qhi,  qlo,  C_ * C_);
    prep_split_kernel<<<1024, 256, 0, stream>>>(k_w,    khi,  klo,  C_ * C_);
    prep_split_kernel<<<1024, 256, 0, stream>>>(v_w,    vhi,  vlo,  C_ * C_);
    prep_split_kernel<<<1024, 256, 0, stream>>>(proj_w, phi,  plo,  C_ * C_);
    prep_split_kernel<<<4096, 256, 0, stream>>>(fc1_w,  f1hi, f1lo, HID_ * C_);
    prep_split_kernel<<<4096, 256, 0, stream>>>(fc2_w,  f2hi, f2lo, C_ * HID_);

    dim3 gLT(4, 8, 16);      // Cf=512
    dim3 gLTh(4, 32, 16);    // Cf=2048
    dim3 gG(2, 4, 64);       // Cout=512
    dim3 gGf1(2, 16, 64);    // Cout=2048

    // shortcut LIF on x -> xs spikes [z][n][c]
    lif_transpose_kernel<<<gLT, 256, 0, stream>>>(x, spkA, C_);

    // q/k/v: GEMM+BN -> f32 ybuf -> LIF+transpose -> spikes
    gemm_kernel<<<gG, 256, 0, stream>>>(spkA, qhi, qlo, nullptr, q_bn, sc_q, nullptr, ybuf, C_, C_);
    lif_transpose_kernel<<<gLT, 256, 0, stream>>>(ybuf, spkB, C_);
    gemm_kernel<<<gG, 256, 0, stream>>>(spkA, khi, klo, nullptr, k_bn, sc_k, nullptr, ybuf, C_, C_);
    lif_transpose_kernel<<<gLT, 256, 0, stream>>>(ybuf, spkC, C_);
    gemm_kernel<<<gG, 256, 0, stream>>>(spkA, vhi, vlo, nullptr, v_bn, sc_v, nullptr, ybuf, C_, C_);
    lif_transpose_kernel<<<gLT, 256, 0, stream>>>(ybuf, spkD, C_);

    // vh output + kv reduce + talking-heads LIF + att mask
    vh_write_kernel<<<512, 256, 0, stream>>>(spkD, out2);
    kv_presum_kernel<<<64, 256, 0, stream>>>(spkC, spkD, presum);
    kv_lif_mask_kernel<<<32, 256, 0, stream>>>(presum, maskp);
    att_apply_kernel<<<8192, 256, 0, stream>>>(spkB, maskp, spkA);   // att into A (xs dead)

    // proj: GEMM(att) + bias + BN + x residual -> x_attn (in out1 region)
    gemm_kernel<<<gG, 256, 0, stream>>>(spkA, phi, plo, proj_b, proj_bn, sc_proj, x, x_attn, C_, C_);

    // MLP
    lif_transpose_kernel<<<gLT, 256, 0, stream>>>(x_attn, spkA, C_);               // h1 into A
    gemm_kernel<<<gGf1, 256, 0, stream>>>(spkA, f1hi, f1lo, fc1_b, fc1_bn, sc_fc1, nullptr, yfc1, C_, HID_);
    lif_transpose_kernel<<<gLTh, 256, 0, stream>>>(yfc1, h2, HID_);                // h2 into B..E
    gemm_kernel<<<gG, 256, 0, stream>>>(h2, f2hi, f2lo, fc2_b, fc2_bn, sc_fc2, x_attn, out1, HID_, C_);
}

// Round 3
// 440.544 us; speedup vs baseline: 3.7230x; 1.2681x over previous
//
#include <hip/hip_runtime.h>
#include <stdint.h>

#pragma clang fp contract(off)

typedef _Float16 f16x8 __attribute__((ext_vector_type(8)));
typedef float f32x4 __attribute__((ext_vector_type(4)));
typedef unsigned short u16;
typedef u16 u16x8 __attribute__((ext_vector_type(8)));

#define T_   4
#define B_   16
#define C_   512
#define HID_ 2048
#define NPIX 256
#define Z_   64            // T_*B_

// ---------------- workspace layout (bytes) ----------------
constexpr size_t OFF_SC_Q    = 0;         // each sc slot 8KB
constexpr size_t OFF_SC_K    = 8192;
constexpr size_t OFF_SC_V    = 16384;
constexpr size_t OFF_SC_PROJ = 24576;
constexpr size_t OFF_SC_FC1  = 32768;
constexpr size_t OFF_SC_FC2  = 40960;
constexpr size_t OFF_PRESUM  = 65536;     // 64*512 f32 = 128KB
constexpr size_t OFF_MASK    = 196608;    // 64*512 u16 = 64KB
constexpr size_t OFF_W       = 262144;
constexpr size_t WSZ_S       = 524288;    // 512*512*2
constexpr size_t WSZ_L       = 2097152;   // 2048*512*2
constexpr size_t OFF_QHI = OFF_W;
constexpr size_t OFF_QLO = OFF_QHI + WSZ_S;
constexpr size_t OFF_KHI = OFF_QLO + WSZ_S;
constexpr size_t OFF_KLO = OFF_KHI + WSZ_S;
constexpr size_t OFF_VHI = OFF_KLO + WSZ_S;
constexpr size_t OFF_VLO = OFF_VHI + WSZ_S;
constexpr size_t OFF_PHI = OFF_VLO + WSZ_S;
constexpr size_t OFF_PLO = OFF_PHI + WSZ_S;
constexpr size_t OFF_F1HI = OFF_PLO + WSZ_S;
constexpr size_t OFF_F1LO = OFF_F1HI + WSZ_L;
constexpr size_t OFF_F2HI = OFF_F1LO + WSZ_L;
constexpr size_t OFF_F2LO = OFF_F2HI + WSZ_L;
constexpr size_t OFF_SPK  = OFF_F2LO + WSZ_L;
constexpr size_t SPKB     = 16777216;                  // 64*256*512*2
constexpr size_t OFF_SPK_A = OFF_SPK;                  // xs -> att
constexpr size_t OFF_SPK_B = OFF_SPK + SPKB;           // q
constexpr size_t OFF_SPK_C = OFF_SPK + 2*SPKB;         // k
constexpr size_t OFF_SPK_D = OFF_SPK + 3*SPKB;         // v
constexpr size_t OFF_SPK_E = OFF_SPK + 4*SPKB;         // h1
constexpr size_t OFF_H2    = OFF_SPK + 5*SPKB;         // h2: 4*SPKB = 67MB

// ---------------- prep: BN scale ----------------
__global__ void prep_sc_kernel(const float* __restrict__ bn, float* __restrict__ sc, int Cn) {
    int c = blockIdx.x * blockDim.x + threadIdx.x;
    if (c < Cn) sc[c] = bn[c] / sqrtf(bn[3 * Cn + c] + 1e-5f);
}

// ---------------- prep: f16 2-split of fp32 weights (lo pre-scaled by 2^11) ----------------
__global__ void prep_split_kernel(const float* __restrict__ W, u16* __restrict__ hi,
                                  u16* __restrict__ lo, int n) {
    int i = blockIdx.x * 256 + threadIdx.x;
    if (i >= n) return;
    float w = W[i];
    _Float16 h = (_Float16)w;
    float d = w - (float)h;               // exact
    _Float16 l = (_Float16)(d * 2048.0f); // keep lo in f16 normal range
    hi[i] = *(const u16*)&h;
    lo[i] = *(const u16*)&l;
}

// ---------------- LIF + transpose: y[T,B,Cf,N] f32 -> spk[z][n][c] f16 ----------------
__global__ __launch_bounds__(256) void lif_transpose_kernel(
        const float* __restrict__ y, u16* __restrict__ spk, int Cf) {
    __shared__ __align__(16) u16 tile[256 * 72];   // [t*64+nn][72]
    int b  = blockIdx.z;
    int c0 = blockIdx.y * 64;
    int n0 = blockIdx.x * 64;
    int tid = threadIdx.x;
    int nn = tid & 63;
    int cg = tid >> 6;
    size_t tstride = (size_t)B_ * Cf * NPIX;
    for (int e = 0; e < 16; ++e) {
        int ci = cg * 16 + e;
        size_t base = ((size_t)b * Cf + c0 + ci) * NPIX + n0 + nn;
        float v = 0.0f;
        #pragma unroll
        for (int t = 0; t < T_; ++t) {
            float x = y[base + (size_t)t * tstride];
            v = v + (x - v) * 0.5f;
            u16 s = 0;
            if (v >= 1.0f) { s = 0x3C00; v = 0.0f; }
            tile[(t * 64 + nn) * 72 + ci] = s;
        }
    }
    __syncthreads();
    int t = tid >> 6, n2 = tid & 63;
    const u16* srow = &tile[(t * 64 + n2) * 72];
    u16* drow = spk + ((size_t)((t * B_ + b) * NPIX) + n0 + n2) * Cf + c0;
    #pragma unroll
    for (int kk = 0; kk < 8; ++kk)
        *(u16x8*)(drow + kk * 8) = *(const u16x8*)(srow + kk * 8);
}

// ---------------- kv presum: counts of (k & v) over n, per (z,c) ----------------
__global__ void kv_presum_kernel(const u16* __restrict__ k, const u16* __restrict__ v,
                                 float* __restrict__ presum) {
    int z = blockIdx.x;
    int tid = threadIdx.x;
    const uint* kp = (const uint*)(k + (size_t)z * NPIX * C_);
    const uint* vp = (const uint*)(v + (size_t)z * NPIX * C_);
    int s0 = 0, s1 = 0;
    for (int n = 0; n < NPIX; ++n) {
        uint a = kp[n * 256 + tid];
        uint b = vp[n * 256 + tid];
        uint c = a & b;
        s0 += (c >> 10) & 1;
        s1 += (c >> 26) & 1;
    }
    presum[z * C_ + 2 * tid]     = (float)s0;
    presum[z * C_ + 2 * tid + 1] = (float)s1;
}

// ---------------- kv LIF (vth=0.5) -> mask u16 ----------------
__global__ void kv_lif_mask_kernel(const float* __restrict__ presum, u16* __restrict__ mask) {
    int i = blockIdx.x * 256 + threadIdx.x;   // 8192 = B_*C_
    int b = i >> 9, c = i & (C_ - 1);
    float v = 0.0f;
    #pragma unroll
    for (int t = 0; t < T_; ++t) {
        float x = presum[((t * B_ + b) << 9) + c];
        v = v + (x - v) * 0.5f;
        u16 m = 0;
        if (v >= 0.5f) { m = 0xFFFF; v = 0.0f; }
        mask[((t * B_ + b) << 9) + c] = m;
    }
}

// ---------------- att = q & mask (broadcast over n) ----------------
__global__ void att_apply_kernel(const u16* __restrict__ q, const u16* __restrict__ mask,
                                 u16* __restrict__ att) {
    size_t i = (size_t)blockIdx.x * 256 + threadIdx.x;  // over 64*256*128 uint2-groups
    int z  = (int)(i >> 15);
    int c4 = (int)(i & 127);
    uint2 qv = ((const uint2*)q)[i];
    uint2 mv = ((const uint2*)(mask + (size_t)z * C_))[c4];
    uint2 r;
    r.x = qv.x & mv.x;
    r.y = qv.y & mv.y;
    ((uint2*)att)[i] = r;
}

// ---------------- vh output: out2[(z*8+h)][n][ch] = v[z][n][h*64+ch] as f32 ----------------
__global__ void vh_write_kernel(const u16* __restrict__ v, float* __restrict__ out2) {
    int slab = blockIdx.x;           // z*8+h
    int z = slab >> 3, h = slab & 7;
    int tid = threadIdx.x;
    int n = tid >> 2, cg = tid & 3;
    for (int it = 0; it < 4; ++it) {
        int nn = n + it * 64;
        const u16* src = v + ((size_t)z * NPIX + nn) * C_ + h * 64 + cg * 16;
        float* dst = out2 + ((size_t)slab * NPIX + nn) * 64 + cg * 16;
        #pragma unroll
        for (int j = 0; j < 16; ++j) dst[j] = src[j] ? 1.0f : 0.0f;
    }
}

// ---------------- fused MFMA GEMM (+BN,+bias,+res) + LIF + transposed spike write ----------------
// Block: 64 o x 64 p x 4 z (z = t*16+b, wave t owns one z). BK=64.
// mode 0: write spikes only; mode 1: write f32 y (+res) AND spikes; mode 2: f32 (+res) only.
__global__ __launch_bounds__(256, 2) void gemm_fused_kernel(
        const u16* __restrict__ S,     // [64][256][Cin] f16 spikes
        const u16* __restrict__ Whi,   // [Cout][Cin]
        const u16* __restrict__ Wlo,
        const float* __restrict__ bias,
        const float* __restrict__ bnp, // [4][Cout]
        const float* __restrict__ sc,  // [Cout]
        const float* res,              // [z][Cout][256] or null (may alias yout)
        float* yout,                   // [z][Cout][256] (modes 1,2)
        u16* spkout,                   // [z][n][Cout]   (modes 0,1)
        int Cin, int Cout, int mode) {
    __shared__ __align__(16) u16 lds[24576];  // 48KB: Ahi 8KB | Alo 8KB | B0..B3 8KB
    float* ldsf = (float*)lds;
    const int tid  = threadIdx.x;
    const int lane = tid & 63;
    const int w    = tid >> 6;           // wave index = timestep t
    const int r15 = lane & 15, quad = lane >> 4;
    const int b  = blockIdx.z;
    const int o0 = blockIdx.y * 64;
    const int p0 = blockIdx.x * 64;
    const int zt = w * B_ + b;

    f32x4 acc1[4][4], acc2[4][4];
    #pragma unroll
    for (int a = 0; a < 4; ++a)
        #pragma unroll
        for (int c = 0; c < 4; ++c) {
            acc1[a][c] = (f32x4){0.f, 0.f, 0.f, 0.f};
            acc2[a][c] = (f32x4){0.f, 0.f, 0.f, 0.f};
        }

    const int srow = lane >> 3;   // staging row within 8-row group
    const int sj   = lane & 7;    // staging chunk slot
    const u16* gA0 = Whi + (size_t)o0 * Cin;
    const u16* gA1 = Wlo + (size_t)o0 * Cin;

    for (int k0 = 0; k0 < Cin; k0 += 64) {
        __syncthreads();
        #pragma unroll
        for (int e = 0; e < 12; ++e) {
            int g   = w * 12 + e;          // 0..47
            int buf = g >> 3;              // 0=Ahi 1=Alo 2..5=B_t
            int rg  = g & 7;               // 8-row group
            int m   = rg * 8 + srow;       // row 0..63
            int jg  = sj ^ (m & 7);        // XOR-swizzled source chunk
            const u16* src;
            if (buf == 0)      src = gA0 + (size_t)m * Cin + k0 + jg * 8;
            else if (buf == 1) src = gA1 + (size_t)m * Cin + k0 + jg * 8;
            else {
                int t = buf - 2;
                src = S + ((size_t)((t * B_ + b) * NPIX + p0 + m)) * Cin + k0 + jg * 8;
            }
            char* dst = (char*)lds + buf * 8192 + rg * 1024;
            __builtin_amdgcn_global_load_lds(
                (const __attribute__((address_space(1))) void*)(uintptr_t)(const void*)src,
                (__attribute__((address_space(3))) void*)(uintptr_t)(void*)dst,
                16, 0, 0);
        }
        __syncthreads();
        const u16* Bb = lds + (2 + w) * 4096;
        #pragma unroll
        for (int ks = 0; ks < 2; ++ks) {
            int cj = ks * 4 + quad;
            f16x8 af[4], al[4], bf[4];
            #pragma unroll
            for (int mt = 0; mt < 4; ++mt) {
                int m = mt * 16 + r15;
                int ad = m * 64 + ((cj ^ (m & 7)) << 3);
                af[mt] = *(const f16x8*)(lds + ad);
                al[mt] = *(const f16x8*)(lds + 4096 + ad);
            }
            #pragma unroll
            for (int nt = 0; nt < 4; ++nt) {
                int n = nt * 16 + r15;
                int ad = n * 64 + ((cj ^ (n & 7)) << 3);
                bf[nt] = *(const f16x8*)(Bb + ad);
            }
            #pragma unroll
            for (int mt = 0; mt < 4; ++mt)
                #pragma unroll
                for (int nt = 0; nt < 4; ++nt) {
                    acc1[mt][nt] = __builtin_amdgcn_mfma_f32_16x16x32_f16(af[mt], bf[nt], acc1[mt][nt], 0, 0, 0);
                    acc2[mt][nt] = __builtin_amdgcn_mfma_f32_16x16x32_f16(al[mt], bf[nt], acc2[mt][nt], 0, 0, 0);
                }
        }
    }

    // combine splits + bias + BN (+res)
    f32x4 yv[4][4];
    const float inv2048 = 1.0f / 2048.0f;
    #pragma unroll
    for (int mt = 0; mt < 4; ++mt) {
        int ob = o0 + mt * 16 + quad * 4;
        float scv[4], mm[4], bb[4], bv[4];
        #pragma unroll
        for (int r = 0; r < 4; ++r) {
            int o = ob + r;
            scv[r] = sc[o];
            mm[r]  = bnp[2 * Cout + o];
            bb[r]  = bnp[Cout + o];
            bv[r]  = bias ? bias[o] : 0.0f;
        }
        #pragma unroll
        for (int nt = 0; nt < 4; ++nt) {
            int p = p0 + nt * 16 + r15;
            #pragma unroll
            for (int r = 0; r < 4; ++r) {
                float y = acc1[mt][nt][r] + acc2[mt][nt][r] * inv2048 + bv[r];
                float val = (y - mm[r]) * scv[r] + bb[r];
                if (mode != 0) {
                    size_t idx = ((size_t)zt * Cout + ob + r) * NPIX + p;
                    val += res[idx];
                }
                yv[mt][nt][r] = val;
            }
        }
    }
    if (mode != 0) {
        #pragma unroll
        for (int mt = 0; mt < 4; ++mt) {
            int ob = o0 + mt * 16 + quad * 4;
            #pragma unroll
            for (int nt = 0; nt < 4; ++nt) {
                int p = p0 + nt * 16 + r15;
                #pragma unroll
                for (int r = 0; r < 4; ++r)
                    yout[((size_t)zt * Cout + ob + r) * NPIX + p] = yv[mt][nt][r];
            }
        }
    }
    if (mode != 2) {
        // LIF across the 4 waves' timesteps via LDS, two 32-pixel passes
        __syncthreads();
        const int og = tid & 7, pi = tid >> 3;    // og: o-group of 8, pi: 0..31
        #pragma unroll
        for (int ph = 0; ph < 2; ++ph) {
            #pragma unroll
            for (int mt = 0; mt < 4; ++mt) {
                int ol = mt * 16 + quad * 4;
                #pragma unroll
                for (int ntl = 0; ntl < 2; ++ntl) {
                    int nt = 2 * ph + ntl;
                    int pl = nt * 16 + r15 - ph * 32;   // 0..31
                    #pragma unroll
                    for (int r = 0; r < 4; ++r)
                        ldsf[w * 2112 + (ol + r) * 33 + pl] = yv[mt][nt][r];
                }
            }
            __syncthreads();
            u16 sp[4][8];
            #pragma unroll
            for (int jj = 0; jj < 8; ++jj) {
                float v = 0.0f;
                #pragma unroll
                for (int t = 0; t < T_; ++t) {
                    float x = ldsf[t * 2112 + (og * 8 + jj) * 33 + pi];
                    v = v + (x - v) * 0.5f;
                    u16 s = 0;
                    if (v >= 1.0f) { s = 0x3C00; v = 0.0f; }
                    sp[t][jj] = s;
                }
            }
            #pragma unroll
            for (int t = 0; t < T_; ++t) {
                u16x8 vv;
                #pragma unroll
                for (int jj = 0; jj < 8; ++jj) vv[jj] = sp[t][jj];
                *(u16x8*)(spkout + ((size_t)((t * B_ + b) * NPIX + p0 + ph * 32 + pi)) * Cout
                          + o0 + og * 8) = vv;
            }
            __syncthreads();
        }
    }
}

extern "C" void kernel_launch(void* const* d_in, const int* in_sizes, int n_in,
                              void* d_out, int out_size, void* d_ws, size_t ws_size,
                              hipStream_t stream) {
    (void)in_sizes; (void)n_in; (void)out_size; (void)ws_size;
    const float* x       = (const float*)d_in[0];
    const float* q_w     = (const float*)d_in[1];
    const float* k_w     = (const float*)d_in[2];
    const float* v_w     = (const float*)d_in[3];
    const float* proj_w  = (const float*)d_in[4];
    const float* proj_b  = (const float*)d_in[5];
    const float* fc1_w   = (const float*)d_in[6];
    const float* fc1_b   = (const float*)d_in[7];
    const float* fc2_w   = (const float*)d_in[8];
    const float* fc2_b   = (const float*)d_in[9];
    const float* q_bn    = (const float*)d_in[10];
    const float* k_bn    = (const float*)d_in[11];
    const float* v_bn    = (const float*)d_in[12];
    const float* proj_bn = (const float*)d_in[13];
    const float* fc1_bn  = (const float*)d_in[14];
    const float* fc2_bn  = (const float*)d_in[15];

    char* ws = (char*)d_ws;
    float* sc_q    = (float*)(ws + OFF_SC_Q);
    float* sc_k    = (float*)(ws + OFF_SC_K);
    float* sc_v    = (float*)(ws + OFF_SC_V);
    float* sc_proj = (float*)(ws + OFF_SC_PROJ);
    float* sc_fc1  = (float*)(ws + OFF_SC_FC1);
    float* sc_fc2  = (float*)(ws + OFF_SC_FC2);
    float* presum  = (float*)(ws + OFF_PRESUM);
    u16*   maskp   = (u16*)(ws + OFF_MASK);
    u16 *qhi = (u16*)(ws + OFF_QHI), *qlo = (u16*)(ws + OFF_QLO);
    u16 *khi = (u16*)(ws + OFF_KHI), *klo = (u16*)(ws + OFF_KLO);
    u16 *vhi = (u16*)(ws + OFF_VHI), *vlo = (u16*)(ws + OFF_VLO);
    u16 *phi = (u16*)(ws + OFF_PHI), *plo = (u16*)(ws + OFF_PLO);
    u16 *f1hi = (u16*)(ws + OFF_F1HI), *f1lo = (u16*)(ws + OFF_F1LO);
    u16 *f2hi = (u16*)(ws + OFF_F2HI), *f2lo = (u16*)(ws + OFF_F2LO);
    u16* spkA = (u16*)(ws + OFF_SPK_A);   // xs -> att
    u16* spkB = (u16*)(ws + OFF_SPK_B);   // q
    u16* spkC = (u16*)(ws + OFF_SPK_C);   // k
    u16* spkD = (u16*)(ws + OFF_SPK_D);   // v
    u16* spkE = (u16*)(ws + OFF_SPK_E);   // h1
    u16* h2   = (u16*)(ws + OFF_H2);      // h2 (67MB)

    float* out1 = (float*)d_out;
    float* out2 = out1 + 8388608;
    float* x_attn = out1;                 // x_attn lives in out1 until fc2 overwrites in-place

    // BN scales
    prep_sc_kernel<<<2, 256, 0, stream>>>(q_bn,    sc_q,    C_);
    prep_sc_kernel<<<2, 256, 0, stream>>>(k_bn,    sc_k,    C_);
    prep_sc_kernel<<<2, 256, 0, stream>>>(v_bn,    sc_v,    C_);
    prep_sc_kernel<<<2, 256, 0, stream>>>(proj_bn, sc_proj, C_);
    prep_sc_kernel<<<8, 256, 0, stream>>>(fc1_bn,  sc_fc1,  HID_);
    prep_sc_kernel<<<2, 256, 0, stream>>>(fc2_bn,  sc_fc2,  C_);

    // weight splits
    prep_split_kernel<<<1024, 256, 0, stream>>>(q_w,    qhi,  qlo,  C_ * C_);
    prep_split_kernel<<<1024, 256, 0, stream>>>(k_w,    khi,  klo,  C_ * C_);
    prep_split_kernel<<<1024, 256, 0, stream>>>(v_w,    vhi,  vlo,  C_ * C_);
    prep_split_kernel<<<1024, 256, 0, stream>>>(proj_w, phi,  plo,  C_ * C_);
    prep_split_kernel<<<4096, 256, 0, stream>>>(fc1_w,  f1hi, f1lo, HID_ * C_);
    prep_split_kernel<<<4096, 256, 0, stream>>>(fc2_w,  f2hi, f2lo, C_ * HID_);

    dim3 gLT(4, 8, 16);       // lif_transpose on x (Cf=512)
    dim3 gG(4, 8, 16);        // fused gemm, Cout=512:  4 p-tiles, 8 o-tiles, 16 b
    dim3 gGf1(4, 32, 16);     // fused gemm, Cout=2048

    // shortcut LIF on x -> xs spikes [z][n][c]
    lif_transpose_kernel<<<gLT, 256, 0, stream>>>(x, spkA, C_);

    // q/k/v: fused GEMM+BN+LIF -> spikes (no f32 intermediate)
    gemm_fused_kernel<<<gG, 256, 0, stream>>>(spkA, qhi, qlo, nullptr, q_bn, sc_q,
                                              nullptr, nullptr, spkB, C_, C_, 0);
    gemm_fused_kernel<<<gG, 256, 0, stream>>>(spkA, khi, klo, nullptr, k_bn, sc_k,
                                              nullptr, nullptr, spkC, C_, C_, 0);
    gemm_fused_kernel<<<gG, 256, 0, stream>>>(spkA, vhi, vlo, nullptr, v_bn, sc_v,
                                              nullptr, nullptr, spkD, C_, C_, 0);

    // vh output + kv reduce + talking-heads LIF + att mask
    vh_write_kernel<<<512, 256, 0, stream>>>(spkD, out2);
    kv_presum_kernel<<<64, 256, 0, stream>>>(spkC, spkD, presum);
    kv_lif_mask_kernel<<<32, 256, 0, stream>>>(presum, maskp);
    att_apply_kernel<<<8192, 256, 0, stream>>>(spkB, maskp, spkA);   // att into A (xs dead)

    // proj: GEMM(att)+bias+BN + x residual -> x_attn f32 AND h1 spikes
    gemm_fused_kernel<<<gG, 256, 0, stream>>>(spkA, phi, plo, proj_b, proj_bn, sc_proj,
                                              x, x_attn, spkE, C_, C_, 1);

    // fc1: GEMM+bias+BN+LIF -> h2 spikes (no 134MB f32 round-trip)
    gemm_fused_kernel<<<gGf1, 256, 0, stream>>>(spkE, f1hi, f1lo, fc1_b, fc1_bn, sc_fc1,
                                                nullptr, nullptr, h2, C_, HID_, 0);

    // fc2: GEMM+bias+BN + x_attn residual -> out1 (in place over x_attn)
    gemm_fused_kernel<<<gG, 256, 0, stream>>>(h2, f2hi, f2lo, fc2_b, fc2_bn, sc_fc2,
                                              x_attn, out1, nullptr, HID_, C_, 2);
}